// Round 1
// baseline (1380.255 us; speedup 1.0000x reference)
//
#include <hip/hip_runtime.h>
#include <math.h>

#define BB 4
#define HH 56
#define WW 56
#define CC 256
#define NN 3136            // HH*WW
#define SS 3137            // 1 + NN
#define NH 8
#define HD 32
#define M_ROWS (BB * SS)   // 12548
#define SCALE 0.17677669529663687f  // 1/sqrt(32)

// ---------------------------------------------------------------------------
// Kernel 1: qkv = x_cat @ qkv_w^T   (fp32 tiled GEMM, NT: dot of two rows)
// x_cat row r: b=r/SS, s=r%SS; s==0 -> cls_token[b], else x[b][s-1]
// Scatters output cols: [0,256)->q, [256,512)->k, [512,768)->v, each [r][c]
// ---------------------------------------------------------------------------
__global__ __launch_bounds__(256)
void qkv_gemm(const float* __restrict__ x, const float* __restrict__ cls,
              const float* __restrict__ w, float* __restrict__ q,
              float* __restrict__ k, float* __restrict__ v)
{
    __shared__ float Xs[64][17];   // stride 17 breaks pow-2 bank aliasing
    __shared__ float Ws[64][17];
    const int tid = threadIdx.x;
    const int row0 = blockIdx.x * 64;
    const int col0 = blockIdx.y * 64;
    const int tn = tid & 15;    // col group (x4)
    const int tm = tid >> 4;    // row group (x4)

    float acc[4][4] = {};

    const int lr  = tid >> 2;         // 0..63 tile row this thread stages
    const int lk4 = (tid & 3) * 4;    // 0,4,8,12

    const int grow = row0 + lr;
    const float* srcX = nullptr;
    if (grow < M_ROWS) {
        int b = grow / SS, s = grow % SS;
        srcX = (s == 0) ? (cls + b * CC)
                        : (x + ((size_t)b * NN + (s - 1)) * CC);
    }
    const float* srcW = w + (size_t)(col0 + lr) * CC;  // col0+lr < 768 always

    for (int kc = 0; kc < CC; kc += 16) {
        float4 xv = make_float4(0.f, 0.f, 0.f, 0.f);
        if (srcX) xv = *(const float4*)(srcX + kc + lk4);
        float4 wv = *(const float4*)(srcW + kc + lk4);
        // scalar stores (stride-17 rows are not 16B aligned)
        Xs[lr][lk4 + 0] = xv.x; Xs[lr][lk4 + 1] = xv.y;
        Xs[lr][lk4 + 2] = xv.z; Xs[lr][lk4 + 3] = xv.w;
        Ws[lr][lk4 + 0] = wv.x; Ws[lr][lk4 + 1] = wv.y;
        Ws[lr][lk4 + 2] = wv.z; Ws[lr][lk4 + 3] = wv.w;
        __syncthreads();
        #pragma unroll
        for (int kk = 0; kk < 16; ++kk) {
            float a[4], bb[4];
            #pragma unroll
            for (int i = 0; i < 4; ++i) a[i]  = Xs[tm * 4 + i][kk];
            #pragma unroll
            for (int i = 0; i < 4; ++i) bb[i] = Ws[tn * 4 + i][kk];
            #pragma unroll
            for (int i = 0; i < 4; ++i)
                #pragma unroll
                for (int j = 0; j < 4; ++j) acc[i][j] += a[i] * bb[j];
        }
        __syncthreads();
    }

    #pragma unroll
    for (int i = 0; i < 4; ++i) {
        int r = row0 + tm * 4 + i;
        if (r >= M_ROWS) continue;
        #pragma unroll
        for (int j = 0; j < 4; ++j) {
            int col = col0 + tn * 4 + j;
            int part = col >> 8;
            int c = col & 255;
            float* dst = (part == 0) ? q : (part == 1) ? k : v;
            dst[(size_t)r * CC + c] = acc[i][j];
        }
    }
}

// ---------------------------------------------------------------------------
// Kernel 2: attention. One thread = one query (b,h,s); K/V tiles staged in
// LDS. Max-free softmax (logits are tiny: |logit| << fp32 exp range).
// Writes o[b][s][h*32..] = softmax(qK^T*scale) @ V
// ---------------------------------------------------------------------------
__global__ __launch_bounds__(256)
void attn_kernel(const float* __restrict__ q, const float* __restrict__ k,
                 const float* __restrict__ v, float* __restrict__ o)
{
    __shared__ float Ks[64][32];
    __shared__ float Vs[64][32];
    const int tid = threadIdx.x;
    const int h = blockIdx.y;
    const int b = blockIdx.z;
    const int s = blockIdx.x * 256 + tid;

    float4 qr[8];
    if (s < SS) {
        const float* qp = q + ((size_t)b * SS + s) * CC + h * HD;
        #pragma unroll
        for (int i = 0; i < 8; ++i) qr[i] = *(const float4*)(qp + i * 4);
    }
    float4 ov[8] = {};
    float l = 0.f;

    for (int j0 = 0; j0 < SS; j0 += 64) {
        __syncthreads();
        #pragma unroll
        for (int t = 0; t < 2; ++t) {
            int fi = tid + t * 256;          // float4 index, 0..511
            int key = fi >> 3;
            int d4  = (fi & 7) * 4;
            int gk = j0 + key;
            float4 kv = make_float4(0.f, 0.f, 0.f, 0.f);
            float4 vv = make_float4(0.f, 0.f, 0.f, 0.f);
            if (gk < SS) {
                size_t base = ((size_t)b * SS + gk) * CC + h * HD + d4;
                kv = *(const float4*)(k + base);
                vv = *(const float4*)(v + base);
            }
            *(float4*)&Ks[key][d4] = kv;
            *(float4*)&Vs[key][d4] = vv;
        }
        __syncthreads();
        if (s < SS) {
            int jmax = min(64, SS - j0);
            for (int j = 0; j < jmax; ++j) {
                const float4* kr = (const float4*)&Ks[j][0];
                float dot = 0.f;
                #pragma unroll
                for (int i = 0; i < 8; ++i) {
                    float4 kk4 = kr[i];
                    dot += qr[i].x * kk4.x + qr[i].y * kk4.y
                         + qr[i].z * kk4.z + qr[i].w * kk4.w;
                }
                float p = __expf(dot * SCALE);
                l += p;
                const float4* vr = (const float4*)&Vs[j][0];
                #pragma unroll
                for (int i = 0; i < 8; ++i) {
                    float4 vv4 = vr[i];
                    ov[i].x += p * vv4.x; ov[i].y += p * vv4.y;
                    ov[i].z += p * vv4.z; ov[i].w += p * vv4.w;
                }
            }
        }
    }

    if (s < SS) {
        float inv = 1.f / l;
        float* op = o + ((size_t)b * SS + s) * CC + h * HD;
        #pragma unroll
        for (int i = 0; i < 8; ++i) {
            float4 r = ov[i];
            r.x *= inv; r.y *= inv; r.z *= inv; r.w *= inv;
            *(float4*)(op + i * 4) = r;
        }
    }
}

// ---------------------------------------------------------------------------
// Kernel 3: LePE depthwise 5x5 conv (cross-correlation, SAME pad) + bias,
// accumulated into o at rows s>=1. One thread per (b,y,x,c).
// ---------------------------------------------------------------------------
__global__ __launch_bounds__(256)
void lepe_kernel(const float* __restrict__ x, const float* __restrict__ w,
                 const float* __restrict__ bias, float* __restrict__ o)
{
    int g = blockIdx.x * 256 + threadIdx.x;    // < BB*NN*CC (exact)
    int c  = g & 255;
    int sp = g >> 8;                 // b*NN + y*WW + xx
    int xx = sp % WW;
    int y  = (sp / WW) % HH;
    int b  = sp / (WW * HH);
    float acc = bias[c];
    const float* wc = w + c * 25;
    #pragma unroll
    for (int ky = 0; ky < 5; ++ky) {
        int yy = y + ky - 2;
        if (yy < 0 || yy >= HH) continue;
        #pragma unroll
        for (int kx = 0; kx < 5; ++kx) {
            int xp = xx + kx - 2;
            if (xp < 0 || xp >= WW) continue;
            acc += x[(((size_t)b * HH + yy) * WW + xp) * CC + c] * wc[ky * 5 + kx];
        }
    }
    size_t oi = ((size_t)b * SS + 1 + (y * WW + xx)) * CC + c;
    o[oi] += acc;
}

// ---------------------------------------------------------------------------
// Kernel 4: out = o @ proj_w^T + proj_b, scattered to (x_out | cls_out)
// ---------------------------------------------------------------------------
__global__ __launch_bounds__(256)
void proj_gemm(const float* __restrict__ o, const float* __restrict__ w,
               const float* __restrict__ bias, float* __restrict__ out)
{
    __shared__ float Xs[64][17];
    __shared__ float Ws[64][17];
    const int tid = threadIdx.x;
    const int row0 = blockIdx.x * 64;
    const int col0 = blockIdx.y * 64;
    const int tn = tid & 15;
    const int tm = tid >> 4;

    float acc[4][4] = {};

    const int lr  = tid >> 2;
    const int lk4 = (tid & 3) * 4;
    const int grow = row0 + lr;
    const float* srcX = (grow < M_ROWS) ? (o + (size_t)grow * CC) : nullptr;
    const float* srcW = w + (size_t)(col0 + lr) * CC;   // col0+lr < 256

    for (int kc = 0; kc < CC; kc += 16) {
        float4 xv = make_float4(0.f, 0.f, 0.f, 0.f);
        if (srcX) xv = *(const float4*)(srcX + kc + lk4);
        float4 wv = *(const float4*)(srcW + kc + lk4);
        Xs[lr][lk4 + 0] = xv.x; Xs[lr][lk4 + 1] = xv.y;
        Xs[lr][lk4 + 2] = xv.z; Xs[lr][lk4 + 3] = xv.w;
        Ws[lr][lk4 + 0] = wv.x; Ws[lr][lk4 + 1] = wv.y;
        Ws[lr][lk4 + 2] = wv.z; Ws[lr][lk4 + 3] = wv.w;
        __syncthreads();
        #pragma unroll
        for (int kk = 0; kk < 16; ++kk) {
            float a[4], bb[4];
            #pragma unroll
            for (int i = 0; i < 4; ++i) a[i]  = Xs[tm * 4 + i][kk];
            #pragma unroll
            for (int i = 0; i < 4; ++i) bb[i] = Ws[tn * 4 + i][kk];
            #pragma unroll
            for (int i = 0; i < 4; ++i)
                #pragma unroll
                for (int j = 0; j < 4; ++j) acc[i][j] += a[i] * bb[j];
        }
        __syncthreads();
    }

    #pragma unroll
    for (int i = 0; i < 4; ++i) {
        int r = row0 + tm * 4 + i;
        if (r >= M_ROWS) continue;
        int b = r / SS, s = r % SS;
        #pragma unroll
        for (int j = 0; j < 4; ++j) {
            int c = col0 + tn * 4 + j;
            float val = acc[i][j] + bias[c];
            if (s == 0)
                out[(size_t)BB * NN * CC + (size_t)b * CC + c] = val;       // cls_out
            else
                out[((size_t)b * NN + (s - 1)) * CC + c] = val;            // x_out
        }
    }
}

extern "C" void kernel_launch(void* const* d_in, const int* in_sizes, int n_in,
                              void* d_out, int out_size, void* d_ws, size_t ws_size,
                              hipStream_t stream)
{
    const float* x      = (const float*)d_in[0];
    const float* cls    = (const float*)d_in[1];
    const float* qkv_w  = (const float*)d_in[2];
    const float* proj_w = (const float*)d_in[3];
    const float* proj_b = (const float*)d_in[4];
    const float* lepe_w = (const float*)d_in[5];
    const float* lepe_b = (const float*)d_in[6];
    float* out = (float*)d_out;

    float* ws = (float*)d_ws;
    const size_t buf = (size_t)M_ROWS * CC;     // 3,212,288 floats
    float* q = ws;
    float* k = q + buf;
    float* v = k + buf;
    // o aliases q if the workspace can't hold a 4th buffer (safe: the only
    // reader of q[r][h*32..] is the unique block that writes o[r][h*32..],
    // and it reads q before its first o write).
    float* o = (ws_size >= 4 * buf * sizeof(float)) ? (v + buf) : q;

    qkv_gemm<<<dim3(197, 12), 256, 0, stream>>>(x, cls, qkv_w, q, k, v);
    attn_kernel<<<dim3(13, NH, BB), 256, 0, stream>>>(q, k, v, o);
    lepe_kernel<<<12544, 256, 0, stream>>>(x, lepe_w, lepe_b, o);
    proj_gemm<<<dim3(197, 4), 256, 0, stream>>>(o, proj_w, proj_b, out);
}

// Round 2
// 474.607 us; speedup vs baseline: 2.9082x; 2.9082x over previous
//
#include <hip/hip_runtime.h>
#include <math.h>

#define BB 4
#define HH 56
#define WW 56
#define CC 256
#define NN 3136            // HH*WW
#define SS 3137            // 1 + NN
#define NH 8
#define HD 32
#define M_ROWS (BB * SS)   // 12548
#define SPAD 3200          // padded S for vt rows
#define SCALE 0.17677669529663687f  // 1/sqrt(32)

typedef short short8 __attribute__((ext_vector_type(8)));   // 8 bf16 (4 VGPRs)
typedef float f32x4  __attribute__((ext_vector_type(4)));   // MFMA C/D

static __device__ __forceinline__ unsigned short f2bf(float f) {
    union { float f; unsigned u; } a; a.f = f;
    unsigned r = a.u + 0x7FFF + ((a.u >> 16) & 1);   // RNE
    return (unsigned short)(r >> 16);
}

// ---------------------------------------------------------------------------
// Kernel 1: qkv = x_cat @ qkv_w^T (fp32 accumulate), emitting:
//   qb [r][256] bf16, kb [r][256] bf16, vt [(b*NH+h)*HD+d][SPAD] bf16 (V^T)
// ---------------------------------------------------------------------------
__global__ __launch_bounds__(256)
void qkv_gemm(const float* __restrict__ x, const float* __restrict__ cls,
              const float* __restrict__ w, unsigned short* __restrict__ qb,
              unsigned short* __restrict__ kb, unsigned short* __restrict__ vt)
{
    __shared__ float Xs[64][17];
    __shared__ float Ws[64][17];
    const int tid = threadIdx.x;
    const int row0 = blockIdx.x * 64;
    const int col0 = blockIdx.y * 64;
    const int tn = tid & 15;
    const int tm = tid >> 4;

    float acc[4][4] = {};

    const int lr  = tid >> 2;
    const int lk4 = (tid & 3) * 4;

    const int grow = row0 + lr;
    const float* srcX = nullptr;
    if (grow < M_ROWS) {
        int b = grow / SS, s = grow % SS;
        srcX = (s == 0) ? (cls + b * CC)
                        : (x + ((size_t)b * NN + (s - 1)) * CC);
    }
    const float* srcW = w + (size_t)(col0 + lr) * CC;

    for (int kc = 0; kc < CC; kc += 16) {
        float4 xv = make_float4(0.f, 0.f, 0.f, 0.f);
        if (srcX) xv = *(const float4*)(srcX + kc + lk4);
        float4 wv = *(const float4*)(srcW + kc + lk4);
        Xs[lr][lk4 + 0] = xv.x; Xs[lr][lk4 + 1] = xv.y;
        Xs[lr][lk4 + 2] = xv.z; Xs[lr][lk4 + 3] = xv.w;
        Ws[lr][lk4 + 0] = wv.x; Ws[lr][lk4 + 1] = wv.y;
        Ws[lr][lk4 + 2] = wv.z; Ws[lr][lk4 + 3] = wv.w;
        __syncthreads();
        #pragma unroll
        for (int kk = 0; kk < 16; ++kk) {
            float a[4], bb[4];
            #pragma unroll
            for (int i = 0; i < 4; ++i) a[i]  = Xs[tm * 4 + i][kk];
            #pragma unroll
            for (int i = 0; i < 4; ++i) bb[i] = Ws[tn * 4 + i][kk];
            #pragma unroll
            for (int i = 0; i < 4; ++i)
                #pragma unroll
                for (int j = 0; j < 4; ++j) acc[i][j] += a[i] * bb[j];
        }
        __syncthreads();
    }

    #pragma unroll
    for (int i = 0; i < 4; ++i) {
        int r = row0 + tm * 4 + i;
        if (r >= M_ROWS) continue;
        #pragma unroll
        for (int j = 0; j < 4; ++j) {
            int col = col0 + tn * 4 + j;
            unsigned short bf = f2bf(acc[i][j]);
            if (col < 256) {
                qb[(size_t)r * CC + col] = bf;
            } else if (col < 512) {
                kb[(size_t)r * CC + (col - 256)] = bf;
            } else {
                int cc = col - 512;
                int h = cc >> 5, d = cc & 31;
                int b = r / SS, s = r % SS;
                vt[((size_t)(b * NH + h) * HD + d) * SPAD + s] = bf;
            }
        }
    }
}

// ---------------------------------------------------------------------------
// Kernel 2: bf16 MFMA flash attention (max-free softmax; logits are tiny).
// Block = (b, h, 64 q-rows); 4 waves x 16 rows. K/V 64-key tiles in LDS.
//   S  = Q(16x32) @ K^T       -> 4x mfma_f32_16x16x32_bf16
//   P  = exp(S*scale)         -> bf16, LDS round-trip to A-layout (m120)
//   O += P(16x64) @ V(64x32)  -> 4x mfma
// o written fp32 [b*SS+s][h*32+d].
// ---------------------------------------------------------------------------
__global__ __launch_bounds__(256)
void attn_mfma(const unsigned short* __restrict__ qb,
               const unsigned short* __restrict__ kb,
               const unsigned short* __restrict__ vt,
               float* __restrict__ o)
{
    __shared__ unsigned short Ks[64][40];     // [key][d], +8 pad: frag reads 2-way max
    __shared__ unsigned short Vts[32][72];    // [d][key], +8 pad
    __shared__ unsigned short Ps[4][16][72];  // per-wave P tile [row][key], +8 pad

    const int tid  = threadIdx.x;
    const int w    = tid >> 6;
    const int lane = tid & 63;
    const int lo   = lane & 15;
    const int hi   = lane >> 4;
    const int h = blockIdx.y;
    const int b = blockIdx.z;
    const int q0 = blockIdx.x * 64 + w * 16;

    // Q A-frag: A[m=lo][k=hi*8+j]  (invalid rows clamped; stores masked later)
    const int qrow = min(q0 + lo, SS - 1);
    const short8 qa = *(const short8*)(qb + ((size_t)(b * SS + qrow)) * CC + h * HD + hi * 8);

    f32x4 oacc0 = {0.f, 0.f, 0.f, 0.f};
    f32x4 oacc1 = {0.f, 0.f, 0.f, 0.f};
    float lp[4] = {0.f, 0.f, 0.f, 0.f};

    // staging coords (hoisted)
    const int skey = tid >> 2, sd0 = (tid & 3) * 8;            // K: 64 x 4 chunks
    const int svd  = tid >> 3, sc0 = (tid & 7) * 8;            // V: 32 x 8 chunks
    const unsigned short* vrow = vt + ((size_t)((b * NH + h) * HD + svd)) * SPAD;

    for (int k0 = 0; k0 < SS; k0 += 64) {
        __syncthreads();
        {
            int gk = k0 + skey;
            short8 kv = {};
            if (gk < SS)
                kv = *(const short8*)(kb + ((size_t)(b * SS + gk)) * CC + h * HD + sd0);
            *(short8*)&Ks[skey][sd0] = kv;
            short8 vv = *(const short8*)(vrow + k0 + sc0);   // pad region: p==0 kills it
            *(short8*)&Vts[svd][sc0] = vv;
        }
        __syncthreads();

        // S = Q K^T, softmax numerator, P -> LDS
        #pragma unroll
        for (int g = 0; g < 4; ++g) {
            short8 kf = *(const short8*)&Ks[g * 16 + lo][hi * 8];
            f32x4 s = __builtin_amdgcn_mfma_f32_16x16x32_bf16(
                          qa, kf, (f32x4){0.f, 0.f, 0.f, 0.f}, 0, 0, 0);
            int key = k0 + g * 16 + lo;
            #pragma unroll
            for (int r = 0; r < 4; ++r) {
                float p = (key < SS) ? __expf(s[r] * SCALE) : 0.f;
                lp[r] += p;
                Ps[w][hi * 4 + r][g * 16 + lo] = f2bf(p);
            }
        }

        // P A-frags + V B-frags, O += P @ V
        short8 pa0 = *(const short8*)&Ps[w][lo][hi * 8];
        short8 pa1 = *(const short8*)&Ps[w][lo][32 + hi * 8];
        short8 vf00 = *(const short8*)&Vts[lo][hi * 8];
        short8 vf01 = *(const short8*)&Vts[lo][32 + hi * 8];
        short8 vf10 = *(const short8*)&Vts[16 + lo][hi * 8];
        short8 vf11 = *(const short8*)&Vts[16 + lo][32 + hi * 8];
        oacc0 = __builtin_amdgcn_mfma_f32_16x16x32_bf16(pa0, vf00, oacc0, 0, 0, 0);
        oacc0 = __builtin_amdgcn_mfma_f32_16x16x32_bf16(pa1, vf01, oacc0, 0, 0, 0);
        oacc1 = __builtin_amdgcn_mfma_f32_16x16x32_bf16(pa0, vf10, oacc1, 0, 0, 0);
        oacc1 = __builtin_amdgcn_mfma_f32_16x16x32_bf16(pa1, vf11, oacc1, 0, 0, 0);
    }

    // reduce l across the 16 lanes sharing hi (cols of the C-frag)
    #pragma unroll
    for (int r = 0; r < 4; ++r) {
        float v = lp[r];
        v += __shfl_xor(v, 1);
        v += __shfl_xor(v, 2);
        v += __shfl_xor(v, 4);
        v += __shfl_xor(v, 8);
        lp[r] = v;
    }

    // store O: row = q0 + hi*4 + r, cols lo and 16+lo
    #pragma unroll
    for (int r = 0; r < 4; ++r) {
        int row = q0 + hi * 4 + r;
        if (row < SS) {
            float inv = 1.f / lp[r];
            float* op = o + ((size_t)(b * SS + row)) * CC + h * HD;
            op[lo]      = oacc0[r] * inv;
            op[16 + lo] = oacc1[r] * inv;
        }
    }
}

// ---------------------------------------------------------------------------
// Kernel 3: LePE depthwise 5x5 conv + bias, accumulated into o rows s>=1.
// ---------------------------------------------------------------------------
__global__ __launch_bounds__(256)
void lepe_kernel(const float* __restrict__ x, const float* __restrict__ w,
                 const float* __restrict__ bias, float* __restrict__ o)
{
    int g = blockIdx.x * 256 + threadIdx.x;
    int c  = g & 255;
    int sp = g >> 8;
    int xx = sp % WW;
    int y  = (sp / WW) % HH;
    int b  = sp / (WW * HH);
    float acc = bias[c];
    const float* wc = w + c * 25;
    #pragma unroll
    for (int ky = 0; ky < 5; ++ky) {
        int yy = y + ky - 2;
        if (yy < 0 || yy >= HH) continue;
        #pragma unroll
        for (int kx = 0; kx < 5; ++kx) {
            int xp = xx + kx - 2;
            if (xp < 0 || xp >= WW) continue;
            acc += x[(((size_t)b * HH + yy) * WW + xp) * CC + c] * wc[ky * 5 + kx];
        }
    }
    size_t oi = ((size_t)b * SS + 1 + (y * WW + xx)) * CC + c;
    o[oi] += acc;
}

// ---------------------------------------------------------------------------
// Kernel 4: out = o @ proj_w^T + proj_b, scattered to (x_out | cls_out)
// ---------------------------------------------------------------------------
__global__ __launch_bounds__(256)
void proj_gemm(const float* __restrict__ o, const float* __restrict__ w,
               const float* __restrict__ bias, float* __restrict__ out)
{
    __shared__ float Xs[64][17];
    __shared__ float Ws[64][17];
    const int tid = threadIdx.x;
    const int row0 = blockIdx.x * 64;
    const int col0 = blockIdx.y * 64;
    const int tn = tid & 15;
    const int tm = tid >> 4;

    float acc[4][4] = {};

    const int lr  = tid >> 2;
    const int lk4 = (tid & 3) * 4;
    const int grow = row0 + lr;
    const float* srcX = (grow < M_ROWS) ? (o + (size_t)grow * CC) : nullptr;
    const float* srcW = w + (size_t)(col0 + lr) * CC;

    for (int kc = 0; kc < CC; kc += 16) {
        float4 xv = make_float4(0.f, 0.f, 0.f, 0.f);
        if (srcX) xv = *(const float4*)(srcX + kc + lk4);
        float4 wv = *(const float4*)(srcW + kc + lk4);
        Xs[lr][lk4 + 0] = xv.x; Xs[lr][lk4 + 1] = xv.y;
        Xs[lr][lk4 + 2] = xv.z; Xs[lr][lk4 + 3] = xv.w;
        Ws[lr][lk4 + 0] = wv.x; Ws[lr][lk4 + 1] = wv.y;
        Ws[lr][lk4 + 2] = wv.z; Ws[lr][lk4 + 3] = wv.w;
        __syncthreads();
        #pragma unroll
        for (int kk = 0; kk < 16; ++kk) {
            float a[4], bb[4];
            #pragma unroll
            for (int i = 0; i < 4; ++i) a[i]  = Xs[tm * 4 + i][kk];
            #pragma unroll
            for (int i = 0; i < 4; ++i) bb[i] = Ws[tn * 4 + i][kk];
            #pragma unroll
            for (int i = 0; i < 4; ++i)
                #pragma unroll
                for (int j = 0; j < 4; ++j) acc[i][j] += a[i] * bb[j];
        }
        __syncthreads();
    }

    #pragma unroll
    for (int i = 0; i < 4; ++i) {
        int r = row0 + tm * 4 + i;
        if (r >= M_ROWS) continue;
        int b = r / SS, s = r % SS;
        #pragma unroll
        for (int j = 0; j < 4; ++j) {
            int c = col0 + tn * 4 + j;
            float val = acc[i][j] + bias[c];
            if (s == 0)
                out[(size_t)BB * NN * CC + (size_t)b * CC + c] = val;
            else
                out[((size_t)b * NN + (s - 1)) * CC + c] = val;
        }
    }
}

extern "C" void kernel_launch(void* const* d_in, const int* in_sizes, int n_in,
                              void* d_out, int out_size, void* d_ws, size_t ws_size,
                              hipStream_t stream)
{
    const float* x      = (const float*)d_in[0];
    const float* cls    = (const float*)d_in[1];
    const float* qkv_w  = (const float*)d_in[2];
    const float* proj_w = (const float*)d_in[3];
    const float* proj_b = (const float*)d_in[4];
    const float* lepe_w = (const float*)d_in[5];
    const float* lepe_b = (const float*)d_in[6];
    float* out = (float*)d_out;

    char* ws = (char*)d_ws;
    const size_t bf_buf = (size_t)M_ROWS * CC * sizeof(unsigned short); // 6,424,576 B
    const size_t vt_buf = (size_t)BB * NH * HD * SPAD * sizeof(unsigned short); // 6,553,600 B
    unsigned short* qb = (unsigned short*)(ws);
    unsigned short* kb = (unsigned short*)(ws + bf_buf);
    unsigned short* vt = (unsigned short*)(ws + 2 * bf_buf);
    float*          o  = (float*)(ws + 2 * bf_buf + vt_buf);   // fp32, 12,849,152 B
    // total ~32.3 MB (round-1 config proved ws_size >= 38.5 MB)

    qkv_gemm<<<dim3(197, 12), 256, 0, stream>>>(x, cls, qkv_w, qb, kb, vt);
    attn_mfma<<<dim3(50, NH, BB), 256, 0, stream>>>(qb, kb, vt, o);
    lepe_kernel<<<12544, 256, 0, stream>>>(x, lepe_w, lepe_b, o);
    proj_gemm<<<dim3(197, 4), 256, 0, stream>>>(o, proj_w, proj_b, out);
}

// Round 3
// 365.253 us; speedup vs baseline: 3.7789x; 1.2994x over previous
//
#include <hip/hip_runtime.h>
#include <math.h>

#define BB 4
#define HH 56
#define WW 56
#define CC 256
#define NN 3136            // HH*WW
#define SS 3137            // 1 + NN
#define NH 8
#define HD 32
#define M_ROWS (BB * SS)   // 12548
#define SPAD 3200          // padded S for vt rows
#define SCALE 0.17677669529663687f  // 1/sqrt(32)

typedef short short8 __attribute__((ext_vector_type(8)));   // 8 bf16 (4 VGPRs)
typedef float f32x4  __attribute__((ext_vector_type(4)));   // MFMA C/D

static __device__ __forceinline__ unsigned short f2bf(float f) {
    union { float f; unsigned u; } a; a.f = f;
    unsigned r = a.u + 0x7FFF + ((a.u >> 16) & 1);   // RNE
    return (unsigned short)(r >> 16);
}
static __device__ __forceinline__ float bf2f(unsigned short h) {
    union { unsigned u; float f; } a; a.u = ((unsigned)h) << 16; return a.f;
}

// ---------------------------------------------------------------------------
// Kernel 0: prepare — xb = bf16(x_cat) [M_ROWS][256], wb = bf16(qkv_w)
// ---------------------------------------------------------------------------
__global__ __launch_bounds__(256)
void prepare(const float* __restrict__ x, const float* __restrict__ cls,
             const float* __restrict__ qkv_w,
             unsigned short* __restrict__ xb, unsigned short* __restrict__ wb)
{
    int blk = blockIdx.x, c = threadIdx.x;
    if (blk < M_ROWS) {
        int b = blk / SS, s = blk % SS;
        const float* src = (s == 0) ? (cls + (size_t)b * CC)
                                    : (x + ((size_t)b * NN + (s - 1)) * CC);
        xb[(size_t)blk * CC + c] = f2bf(src[c]);
    } else {
        int r = blk - M_ROWS;   // 0..767
        wb[(size_t)r * CC + c] = f2bf(qkv_w[(size_t)r * CC + c]);
    }
}

// ---------------------------------------------------------------------------
// Kernel 1: qkv bf16 MFMA GEMM: [12548x256] @ [768x256]^T
// 128x128 tile, BK=64, 4 waves x (64x64). Epilogue scatters (block-uniform):
//   cols [0,256):   qb = bf16(acc*SCALE)   (scale folded here)
//   cols [256,512): kb
//   cols [512,768): vt[(b*8+h)*32+d][s]  (V^T)
// ---------------------------------------------------------------------------
__global__ __launch_bounds__(256)
void qkv_mfma(const unsigned short* __restrict__ xb,
              const unsigned short* __restrict__ wb,
              unsigned short* __restrict__ qb, unsigned short* __restrict__ kb,
              unsigned short* __restrict__ vt)
{
    __shared__ unsigned short As[128][72];   // stride 72: balanced b128 bank quads
    __shared__ unsigned short Bs[128][72];
    const int tid = threadIdx.x;
    const int w = tid >> 6, lane = tid & 63, lo = lane & 15, hi = lane >> 4;
    const int row0 = blockIdx.x * 128, col0 = blockIdx.y * 128;
    const int wm = (w & 1) * 64, wn = (w >> 1) * 64;

    f32x4 acc[4][4] = {};

    for (int k0 = 0; k0 < CC; k0 += 64) {
        __syncthreads();
        #pragma unroll
        for (int i = 0; i < 4; ++i) {
            int chunk = tid + i * 256;          // 0..1023
            int row = chunk >> 3, c8 = (chunk & 7) * 8;
            short8 av = {};
            int gr = row0 + row;
            if (gr < M_ROWS)
                av = *(const short8*)(xb + (size_t)gr * CC + k0 + c8);
            *(short8*)&As[row][c8] = av;
            short8 bv = *(const short8*)(wb + (size_t)(col0 + row) * CC + k0 + c8);
            *(short8*)&Bs[row][c8] = bv;
        }
        __syncthreads();
        #pragma unroll
        for (int kk = 0; kk < 64; kk += 32) {
            short8 af[4], bf_[4];
            #pragma unroll
            for (int m = 0; m < 4; ++m)
                af[m] = *(const short8*)&As[wm + m * 16 + lo][kk + hi * 8];
            #pragma unroll
            for (int n = 0; n < 4; ++n)
                bf_[n] = *(const short8*)&Bs[wn + n * 16 + lo][kk + hi * 8];
            #pragma unroll
            for (int m = 0; m < 4; ++m)
                #pragma unroll
                for (int n = 0; n < 4; ++n)
                    acc[m][n] = __builtin_amdgcn_mfma_f32_16x16x32_bf16(
                                    af[m], bf_[n], acc[m][n], 0, 0, 0);
        }
    }

    const int part = col0 >> 8;   // 0=q, 1=k, 2=v (block-uniform)
    #pragma unroll
    for (int m = 0; m < 4; ++m) {
        #pragma unroll
        for (int rr = 0; rr < 4; ++rr) {
            int r = row0 + wm + m * 16 + hi * 4 + rr;
            if (r >= M_ROWS) continue;
            #pragma unroll
            for (int n = 0; n < 4; ++n) {
                int colq = col0 + wn + n * 16 + lo;
                int cc = colq & 255;
                float val = acc[m][n][rr];
                if (part == 0) {
                    qb[(size_t)r * CC + cc] = f2bf(val * SCALE);
                } else if (part == 1) {
                    kb[(size_t)r * CC + cc] = f2bf(val);
                } else {
                    int hh = cc >> 5, d = cc & 31;
                    int b = r / SS, s = r % SS;
                    vt[((size_t)((b * NH + hh) * HD + d)) * SPAD + s] = f2bf(val);
                }
            }
        }
    }
}

// ---------------------------------------------------------------------------
// Kernel 2: bf16 MFMA flash attention. Block = (b,h,128 q-rows), 4 waves x 32.
// SCALE pre-folded into qb. Max-free softmax (logits tiny).
// ---------------------------------------------------------------------------
__global__ __launch_bounds__(256)
void attn_mfma(const unsigned short* __restrict__ qb,
               const unsigned short* __restrict__ kb,
               const unsigned short* __restrict__ vt,
               float* __restrict__ o)
{
    __shared__ unsigned short Ks[64][40];
    __shared__ unsigned short Vts[32][72];
    __shared__ unsigned short Ps[4][32][72];

    const int tid  = threadIdx.x;
    const int w    = tid >> 6;
    const int lane = tid & 63;
    const int lo   = lane & 15;
    const int hi   = lane >> 4;
    const int h = blockIdx.y;
    const int b = blockIdx.z;
    const int q0w = blockIdx.x * 128 + w * 32;

    const int r0 = min(q0w + lo, SS - 1);
    const int r1 = min(q0w + 16 + lo, SS - 1);
    short8 qa[2];
    qa[0] = *(const short8*)(qb + ((size_t)(b * SS + r0)) * CC + h * HD + hi * 8);
    qa[1] = *(const short8*)(qb + ((size_t)(b * SS + r1)) * CC + h * HD + hi * 8);

    f32x4 oacc[2][2] = {};
    float lp[2][4] = {};

    const int skey = tid >> 2, sd0 = (tid & 3) * 8;
    const int svd  = tid >> 3, sc0 = (tid & 7) * 8;
    const unsigned short* vrow = vt + ((size_t)((b * NH + h) * HD + svd)) * SPAD;

    for (int k0 = 0; k0 < SS; k0 += 64) {
        __syncthreads();
        {
            int gk = k0 + skey;
            short8 kv = {};
            if (gk < SS)
                kv = *(const short8*)(kb + ((size_t)(b * SS + gk)) * CC + h * HD + sd0);
            *(short8*)&Ks[skey][sd0] = kv;
            short8 vv = *(const short8*)(vrow + k0 + sc0);
            *(short8*)&Vts[svd][sc0] = vv;
        }
        __syncthreads();

        short8 kf[4];
        #pragma unroll
        for (int g = 0; g < 4; ++g)
            kf[g] = *(const short8*)&Ks[g * 16 + lo][hi * 8];

        #pragma unroll
        for (int rg = 0; rg < 2; ++rg) {
            #pragma unroll
            for (int g = 0; g < 4; ++g) {
                f32x4 s = __builtin_amdgcn_mfma_f32_16x16x32_bf16(
                              qa[rg], kf[g], (f32x4){0.f, 0.f, 0.f, 0.f}, 0, 0, 0);
                int key = k0 + g * 16 + lo;
                #pragma unroll
                for (int r = 0; r < 4; ++r) {
                    float p = (key < SS) ? __expf(s[r]) : 0.f;
                    lp[rg][r] += p;
                    Ps[w][rg * 16 + hi * 4 + r][g * 16 + lo] = f2bf(p);
                }
            }
        }

        short8 vf[2][2];
        #pragma unroll
        for (int d = 0; d < 2; ++d) {
            vf[d][0] = *(const short8*)&Vts[d * 16 + lo][hi * 8];
            vf[d][1] = *(const short8*)&Vts[d * 16 + lo][32 + hi * 8];
        }
        #pragma unroll
        for (int rg = 0; rg < 2; ++rg) {
            short8 pa0 = *(const short8*)&Ps[w][rg * 16 + lo][hi * 8];
            short8 pa1 = *(const short8*)&Ps[w][rg * 16 + lo][32 + hi * 8];
            #pragma unroll
            for (int d = 0; d < 2; ++d) {
                oacc[rg][d] = __builtin_amdgcn_mfma_f32_16x16x32_bf16(
                                  pa0, vf[d][0], oacc[rg][d], 0, 0, 0);
                oacc[rg][d] = __builtin_amdgcn_mfma_f32_16x16x32_bf16(
                                  pa1, vf[d][1], oacc[rg][d], 0, 0, 0);
            }
        }
    }

    #pragma unroll
    for (int rg = 0; rg < 2; ++rg)
        #pragma unroll
        for (int r = 0; r < 4; ++r) {
            float v = lp[rg][r];
            v += __shfl_xor(v, 1);
            v += __shfl_xor(v, 2);
            v += __shfl_xor(v, 4);
            v += __shfl_xor(v, 8);
            lp[rg][r] = v;
        }

    #pragma unroll
    for (int rg = 0; rg < 2; ++rg)
        #pragma unroll
        for (int r = 0; r < 4; ++r) {
            int row = q0w + rg * 16 + hi * 4 + r;
            if (row < SS) {
                float inv = 1.f / lp[rg][r];
                float* op = o + ((size_t)(b * SS + row)) * CC + h * HD;
                op[lo]      = oacc[rg][0][r] * inv;
                op[16 + lo] = oacc[rg][1][r] * inv;
            }
        }
}

// ---------------------------------------------------------------------------
// Kernel 3: fused LePE(5x5 dw conv + bias) + o split to bf16 hi/lo,
// plus proj_w hi/lo split (blocks >= M_ROWS).
// ---------------------------------------------------------------------------
__global__ __launch_bounds__(256)
void lepe_conv(const float* __restrict__ o, const float* __restrict__ x,
               const float* __restrict__ lepe_w, const float* __restrict__ lepe_b,
               const float* __restrict__ proj_w,
               unsigned short* __restrict__ ohi, unsigned short* __restrict__ olo,
               unsigned short* __restrict__ pwhi, unsigned short* __restrict__ pwlo)
{
    int blk = blockIdx.x, c = threadIdx.x;
    if (blk < M_ROWS) {
        float val = o[(size_t)blk * CC + c];
        int b = blk / SS, s = blk % SS;
        if (s > 0) {
            int sp = s - 1;
            int xx = sp % WW, y = sp / WW;
            float acc = lepe_b[c];
            const float* wc = lepe_w + c * 25;
            #pragma unroll
            for (int ky = 0; ky < 5; ++ky) {
                int yy = y + ky - 2;
                if (yy < 0 || yy >= HH) continue;
                #pragma unroll
                for (int kx = 0; kx < 5; ++kx) {
                    int xp = xx + kx - 2;
                    if (xp < 0 || xp >= WW) continue;
                    acc += x[(((size_t)b * HH + yy) * WW + xp) * CC + c] * wc[ky * 5 + kx];
                }
            }
            val += acc;
        }
        unsigned short h = f2bf(val);
        ohi[(size_t)blk * CC + c] = h;
        olo[(size_t)blk * CC + c] = f2bf(val - bf2f(h));
    } else {
        int r = blk - M_ROWS;   // 0..255
        float v = proj_w[(size_t)r * CC + c];
        unsigned short h = f2bf(v);
        pwhi[(size_t)r * CC + c] = h;
        pwlo[(size_t)r * CC + c] = f2bf(v - bf2f(h));
    }
}

// ---------------------------------------------------------------------------
// Kernel 4: proj split-bf16 MFMA GEMM: out = (o+lepe) @ proj_w^T + b
// acc = Ahi@Whi + Alo@Whi + Ahi@Wlo  (fp32-grade accuracy).
// 64x64 tile, BK=64, 4 waves x (32x32). Scatter to (x_out | cls_out).
// ---------------------------------------------------------------------------
__global__ __launch_bounds__(256)
void proj_mfma(const unsigned short* __restrict__ ohi,
               const unsigned short* __restrict__ olo,
               const unsigned short* __restrict__ pwhi,
               const unsigned short* __restrict__ pwlo,
               const float* __restrict__ bias, float* __restrict__ out)
{
    __shared__ unsigned short Ah[64][72];
    __shared__ unsigned short Al[64][72];
    __shared__ unsigned short Wh[64][72];
    __shared__ unsigned short Wl[64][72];
    const int tid = threadIdx.x;
    const int w = tid >> 6, lane = tid & 63, lo = lane & 15, hi = lane >> 4;
    const int row0 = blockIdx.x * 64, col0 = blockIdx.y * 64;
    const int wm = (w & 1) * 32, wn = (w >> 1) * 32;

    f32x4 acc[2][2] = {};

    for (int k0 = 0; k0 < CC; k0 += 64) {
        __syncthreads();
        #pragma unroll
        for (int i = 0; i < 2; ++i) {
            int chunk = tid + i * 256;          // 0..511
            int row = chunk >> 3, c8 = (chunk & 7) * 8;
            int gr = row0 + row;
            short8 ah = {}, al = {};
            if (gr < M_ROWS) {
                ah = *(const short8*)(ohi + (size_t)gr * CC + k0 + c8);
                al = *(const short8*)(olo + (size_t)gr * CC + k0 + c8);
            }
            *(short8*)&Ah[row][c8] = ah;
            *(short8*)&Al[row][c8] = al;
            int wr = col0 + row;
            *(short8*)&Wh[row][c8] = *(const short8*)(pwhi + (size_t)wr * CC + k0 + c8);
            *(short8*)&Wl[row][c8] = *(const short8*)(pwlo + (size_t)wr * CC + k0 + c8);
        }
        __syncthreads();
        #pragma unroll
        for (int kk = 0; kk < 64; kk += 32) {
            short8 ah[2], al[2], wh[2], wl[2];
            #pragma unroll
            for (int m = 0; m < 2; ++m) {
                ah[m] = *(const short8*)&Ah[wm + m * 16 + lo][kk + hi * 8];
                al[m] = *(const short8*)&Al[wm + m * 16 + lo][kk + hi * 8];
            }
            #pragma unroll
            for (int n = 0; n < 2; ++n) {
                wh[n] = *(const short8*)&Wh[wn + n * 16 + lo][kk + hi * 8];
                wl[n] = *(const short8*)&Wl[wn + n * 16 + lo][kk + hi * 8];
            }
            #pragma unroll
            for (int m = 0; m < 2; ++m)
                #pragma unroll
                for (int n = 0; n < 2; ++n) {
                    acc[m][n] = __builtin_amdgcn_mfma_f32_16x16x32_bf16(
                                    ah[m], wh[n], acc[m][n], 0, 0, 0);
                    acc[m][n] = __builtin_amdgcn_mfma_f32_16x16x32_bf16(
                                    al[m], wh[n], acc[m][n], 0, 0, 0);
                    acc[m][n] = __builtin_amdgcn_mfma_f32_16x16x32_bf16(
                                    ah[m], wl[n], acc[m][n], 0, 0, 0);
                }
        }
    }

    #pragma unroll
    for (int m = 0; m < 2; ++m) {
        #pragma unroll
        for (int rr = 0; rr < 4; ++rr) {
            int r = row0 + wm + m * 16 + hi * 4 + rr;
            if (r >= M_ROWS) continue;
            int b = r / SS, s = r % SS;
            #pragma unroll
            for (int n = 0; n < 2; ++n) {
                int col = col0 + wn + n * 16 + lo;
                float val = acc[m][n][rr] + bias[col];
                if (s == 0)
                    out[(size_t)BB * NN * CC + (size_t)b * CC + col] = val;
                else
                    out[((size_t)b * NN + (s - 1)) * CC + col] = val;
            }
        }
    }
}

extern "C" void kernel_launch(void* const* d_in, const int* in_sizes, int n_in,
                              void* d_out, int out_size, void* d_ws, size_t ws_size,
                              hipStream_t stream)
{
    const float* x      = (const float*)d_in[0];
    const float* cls    = (const float*)d_in[1];
    const float* qkv_w  = (const float*)d_in[2];
    const float* proj_w = (const float*)d_in[3];
    const float* proj_b = (const float*)d_in[4];
    const float* lepe_w = (const float*)d_in[5];
    const float* lepe_b = (const float*)d_in[6];
    float* out = (float*)d_out;

    // Workspace overlay (total 32,251,904 B — same footprint as round 2):
    //   [0        ) qb (6.42M)  -> later ohi
    //   [6424576  ) kb (6.42M)  -> later olo
    //   [12849152 ) vt (6.55M)  -> later pwhi/pwlo
    //   [19402752 ) o fp32 (12.85M); xb+wb live here BEFORE attn writes o
    char* ws = (char*)d_ws;
    unsigned short* qb   = (unsigned short*)(ws + 0);
    unsigned short* kb   = (unsigned short*)(ws + 6424576);
    unsigned short* vt   = (unsigned short*)(ws + 12849152);
    float*          o    = (float*)(ws + 19402752);
    unsigned short* xb   = (unsigned short*)(ws + 19402752);   // aliases o (dead before attn)
    unsigned short* wb   = (unsigned short*)(ws + 25827328);   // aliases o tail
    unsigned short* ohi  = (unsigned short*)(ws + 0);          // aliases qb (dead after attn)
    unsigned short* olo  = (unsigned short*)(ws + 6424576);    // aliases kb
    unsigned short* pwhi = (unsigned short*)(ws + 12849152);   // aliases vt (dead after attn)
    unsigned short* pwlo = (unsigned short*)(ws + 12980224);

    prepare  <<<M_ROWS + 3 * CC, 256, 0, stream>>>(x, cls, qkv_w, xb, wb);
    qkv_mfma <<<dim3(99, 6), 256, 0, stream>>>(xb, wb, qb, kb, vt);
    attn_mfma<<<dim3(25, NH, BB), 256, 0, stream>>>(qb, kb, vt, o);
    lepe_conv<<<M_ROWS + CC, 256, 0, stream>>>(o, x, lepe_w, lepe_b, proj_w,
                                               ohi, olo, pwhi, pwlo);
    proj_mfma<<<dim3(197, 4), 256, 0, stream>>>(ohi, olo, pwhi, pwlo, proj_b, out);
}

// Round 4
// 323.165 us; speedup vs baseline: 4.2711x; 1.1302x over previous
//
#include <hip/hip_runtime.h>
#include <math.h>

#define BB 4
#define HH 56
#define WW 56
#define CC 256
#define NN 3136            // HH*WW
#define SS 3137            // 1 + NN
#define NH 8
#define HD 32
#define M_ROWS (BB * SS)   // 12548
#define SPAD 3200          // padded S for vt rows
#define SCALE 0.17677669529663687f           // 1/sqrt(32)
#define QSCALE (0.17677669529663687f * 1.4426950408889634f)  // fold log2(e): use exp2
#define KT 128             // attention key-tile

typedef short short8 __attribute__((ext_vector_type(8)));   // 8 bf16 (4 VGPRs)
typedef short bf4    __attribute__((ext_vector_type(4)));   // 4 bf16 (2 VGPRs)
typedef float f32x4  __attribute__((ext_vector_type(4)));   // MFMA C/D

static __device__ __forceinline__ unsigned short f2bf(float f) {
    union { float f; unsigned u; } a; a.f = f;
    unsigned r = a.u + 0x7FFF + ((a.u >> 16) & 1);   // RNE
    return (unsigned short)(r >> 16);
}
static __device__ __forceinline__ float bf2f(unsigned short h) {
    union { unsigned u; float f; } a; a.u = ((unsigned)h) << 16; return a.f;
}

// ---------------------------------------------------------------------------
// Kernel 0: prepare — xb = bf16(x_cat) [M_ROWS][256], wb = bf16(qkv_w),
// plus zero vt pad columns [3136,3200) so attention tail keys are exact.
// ---------------------------------------------------------------------------
__global__ __launch_bounds__(256)
void prepare(const float* __restrict__ x, const float* __restrict__ cls,
             const float* __restrict__ qkv_w,
             unsigned short* __restrict__ xb, unsigned short* __restrict__ wb,
             unsigned short* __restrict__ vt)
{
    int blk = blockIdx.x, c = threadIdx.x;
    if (blk < M_ROWS) {
        int b = blk / SS, s = blk % SS;
        const float* src = (s == 0) ? (cls + (size_t)b * CC)
                                    : (x + ((size_t)b * NN + (s - 1)) * CC);
        xb[(size_t)blk * CC + c] = f2bf(src[c]);
    } else if (blk < M_ROWS + 3 * CC) {
        int r = blk - M_ROWS;   // 0..767
        wb[(size_t)r * CC + c] = f2bf(qkv_w[(size_t)r * CC + c]);
    } else {
        // zero vt[row][3136..3199] for all 1024 rows (qkv later writes 3136)
        int base = (blk - (M_ROWS + 3 * CC)) * 4;   // 4 rows per block
        int row = base + (c >> 6);
        int col = 3136 + (c & 63);
        vt[(size_t)row * SPAD + col] = 0;
    }
}

// ---------------------------------------------------------------------------
// Kernel 1: qkv bf16 MFMA GEMM: [12548x256] @ [768x256]^T
// Grid (100,6): x = b0*25 + s-block (batch-aligned M tiles so the V^T
// epilogue's 4-row packs are always 4-aligned in s). Epilogue:
//   cols [0,256):   qb = bf16(acc*QSCALE)  (softmax scale * log2e folded)
//   cols [256,512): kb
//   cols [512,768): vt[(b*8+h)*32+d][s]  (V^T, packed short4 stores)
// ---------------------------------------------------------------------------
__global__ __launch_bounds__(256)
void qkv_mfma(const unsigned short* __restrict__ xb,
              const unsigned short* __restrict__ wb,
              unsigned short* __restrict__ qb, unsigned short* __restrict__ kb,
              unsigned short* __restrict__ vt)
{
    __shared__ unsigned short As[128][72];
    __shared__ unsigned short Bs[128][72];
    const int tid = threadIdx.x;
    const int w = tid >> 6, lane = tid & 63, lo = lane & 15, hi = lane >> 4;
    const int b0 = blockIdx.x / 25;
    const int s0blk = (blockIdx.x % 25) * 128;
    const int col0 = blockIdx.y * 128;
    const int wm = (w & 1) * 64, wn = (w >> 1) * 64;

    f32x4 acc[4][4] = {};

    for (int k0 = 0; k0 < CC; k0 += 64) {
        __syncthreads();
        #pragma unroll
        for (int i = 0; i < 4; ++i) {
            int chunk = tid + i * 256;          // 0..1023
            int row = chunk >> 3, c8 = (chunk & 7) * 8;
            short8 av = {};
            if (s0blk + row < SS)
                av = *(const short8*)(xb + (size_t)(b0 * SS + s0blk + row) * CC + k0 + c8);
            *(short8*)&As[row][c8] = av;
            short8 bv = *(const short8*)(wb + (size_t)(col0 + row) * CC + k0 + c8);
            *(short8*)&Bs[row][c8] = bv;
        }
        __syncthreads();
        #pragma unroll
        for (int kk = 0; kk < 64; kk += 32) {
            short8 af[4], bf_[4];
            #pragma unroll
            for (int m = 0; m < 4; ++m)
                af[m] = *(const short8*)&As[wm + m * 16 + lo][kk + hi * 8];
            #pragma unroll
            for (int n = 0; n < 4; ++n)
                bf_[n] = *(const short8*)&Bs[wn + n * 16 + lo][kk + hi * 8];
            #pragma unroll
            for (int m = 0; m < 4; ++m)
                #pragma unroll
                for (int n = 0; n < 4; ++n)
                    acc[m][n] = __builtin_amdgcn_mfma_f32_16x16x32_bf16(
                                    af[m], bf_[n], acc[m][n], 0, 0, 0);
        }
    }

    const int part = col0 >> 8;   // 0=q, 1=k, 2=v (block-uniform)
    if (part < 2) {
        #pragma unroll
        for (int m = 0; m < 4; ++m) {
            #pragma unroll
            for (int rr = 0; rr < 4; ++rr) {
                int s = s0blk + wm + m * 16 + hi * 4 + rr;
                if (s >= SS) continue;
                size_t r = (size_t)(b0 * SS + s);
                #pragma unroll
                for (int n = 0; n < 4; ++n) {
                    int cc = (col0 + wn + n * 16 + lo) & 255;
                    float val = acc[m][n][rr];
                    if (part == 0) qb[r * CC + cc] = f2bf(val * QSCALE);
                    else           kb[r * CC + cc] = f2bf(val);
                }
            }
        }
    } else {
        #pragma unroll
        for (int m = 0; m < 4; ++m) {
            int s0 = s0blk + wm + m * 16 + hi * 4;   // multiple of 4
            if (s0 >= SS) continue;
            bool fast = (s0 + 3 < SS);
            #pragma unroll
            for (int n = 0; n < 4; ++n) {
                int cc = (col0 + wn + n * 16 + lo) & 255;
                int hh = cc >> 5, d = cc & 31;
                unsigned short* vrow = vt + (size_t)((b0 * NH + hh) * HD + d) * SPAD;
                if (fast) {
                    bf4 pk;
                    pk[0] = (short)f2bf(acc[m][n][0]);
                    pk[1] = (short)f2bf(acc[m][n][1]);
                    pk[2] = (short)f2bf(acc[m][n][2]);
                    pk[3] = (short)f2bf(acc[m][n][3]);
                    *(bf4*)(vrow + s0) = pk;   // 8-B aligned: s0 % 4 == 0
                } else {
                    for (int rr = 0; rr < 4 && s0 + rr < SS; ++rr)
                        vrow[s0 + rr] = f2bf(acc[m][n][rr]);
                }
            }
        }
    }
}

// ---------------------------------------------------------------------------
// Kernel 2: bf16 MFMA flash attention, transposed-S formulation.
//   S^T = K @ Q^T  (16x16x32; C-layout: q=lane&15, key=hi*4+r)
//   P^T = round_half_up(exp2(S^T))  -- packed in-register (v_perm), no LDS
//   O^T += V^T @ P^T (16x16x16; P^T registers ARE the B-operand layout)
// Tail keys: K staged as 0 -> p=1, V^T pad is 0 -> denominator -= 63 exactly.
// Block = (b, h, 128 q); 4 waves x 32 q. KT=128 keys/tile.
// ---------------------------------------------------------------------------
__global__ __launch_bounds__(256)
void attn_mfma(const unsigned short* __restrict__ qb,
               const unsigned short* __restrict__ kb,
               const unsigned short* __restrict__ vt,
               float* __restrict__ o)
{
    __shared__ unsigned short Ks[KT][40];     // 10240 B; b128 reads 2-way max
    __shared__ unsigned short Vts[32][136];   // 8704 B;  b64 reads 2-way max

    const int tid  = threadIdx.x;
    const int w    = tid >> 6;
    const int lane = tid & 63;
    const int lo   = lane & 15;
    const int hi   = lane >> 4;
    const int h = blockIdx.y;
    const int b = blockIdx.z;
    const int q0w = blockIdx.x * 128 + w * 32;

    short8 qa[2];
    #pragma unroll
    for (int qg = 0; qg < 2; ++qg) {
        int row = min(q0w + qg * 16 + lo, SS - 1);
        qa[qg] = *(const short8*)(qb + ((size_t)(b * SS + row)) * CC + h * HD + hi * 8);
    }

    f32x4 oacc[2][2] = {};
    float lp[2] = {0.f, 0.f};

    const int krow = tid >> 2, kd0 = (tid & 3) * 8;    // K staging: 2 rows/thread
    const int vrow = tid >> 4, vk0 = (tid & 15) * 8;   // V staging: 2 rows/thread
    const unsigned short* kp0 = kb + ((size_t)b * SS + krow) * CC + h * HD + kd0;
    const unsigned short* vp0 = vt + ((size_t)((b * NH + h) * HD + vrow)) * SPAD + vk0;

    for (int k0 = 0; k0 < SPAD; k0 += KT) {
        __syncthreads();
        {
            short8 kv0 = {}, kv1 = {};
            if (k0 + krow < SS)      kv0 = *(const short8*)(kp0 + (size_t)k0 * CC);
            if (k0 + 64 + krow < SS) kv1 = *(const short8*)(kp0 + (size_t)(k0 + 64) * CC);
            *(short8*)&Ks[krow][kd0]      = kv0;
            *(short8*)&Ks[64 + krow][kd0] = kv1;
            short8 vv0 = *(const short8*)(vp0 + k0);
            short8 vv1 = *(const short8*)(vp0 + (size_t)16 * SPAD + k0);
            *(short8*)&Vts[vrow][vk0]      = vv0;
            *(short8*)&Vts[16 + vrow][vk0] = vv1;
        }
        __syncthreads();

        #pragma unroll
        for (int g = 0; g < 8; ++g) {
            short8 kf = *(const short8*)&Ks[g * 16 + lo][hi * 8];
            bf4 vf0 = *(const bf4*)&Vts[lo][g * 16 + hi * 4];
            bf4 vf1 = *(const bf4*)&Vts[16 + lo][g * 16 + hi * 4];
            #pragma unroll
            for (int qg = 0; qg < 2; ++qg) {
                f32x4 st = __builtin_amdgcn_mfma_f32_16x16x32_bf16(
                               kf, qa[qg], (f32x4){0.f, 0.f, 0.f, 0.f}, 0, 0, 0);
                float p0 = __builtin_amdgcn_exp2f(st[0]);
                float p1 = __builtin_amdgcn_exp2f(st[1]);
                float p2 = __builtin_amdgcn_exp2f(st[2]);
                float p3 = __builtin_amdgcn_exp2f(st[3]);
                lp[qg] += (p0 + p1) + (p2 + p3);
                // round-half-up bf16 pack: (bits+0x8000)>>16, 2 perms
                unsigned u01 = __builtin_amdgcn_perm(
                    __float_as_uint(p1) + 0x8000u, __float_as_uint(p0) + 0x8000u,
                    0x07060302u);
                unsigned u23 = __builtin_amdgcn_perm(
                    __float_as_uint(p3) + 0x8000u, __float_as_uint(p2) + 0x8000u,
                    0x07060302u);
                union { unsigned u[2]; bf4 s; } pf;
                pf.u[0] = u01; pf.u[1] = u23;
                oacc[qg][0] = __builtin_amdgcn_mfma_f32_16x16x16bf16_1k(
                                  vf0, pf.s, oacc[qg][0], 0, 0, 0);
                oacc[qg][1] = __builtin_amdgcn_mfma_f32_16x16x16bf16_1k(
                                  vf1, pf.s, oacc[qg][1], 0, 0, 0);
            }
        }
    }

    #pragma unroll
    for (int qg = 0; qg < 2; ++qg) {
        float l = lp[qg];
        l += __shfl_xor(l, 16);
        l += __shfl_xor(l, 32);
        float inv = 1.f / (l - 63.f);        // remove the 63 pad keys (p=1 each)
        int row = q0w + qg * 16 + lo;
        if (row < SS) {
            float* op = o + ((size_t)(b * SS + row)) * CC + h * HD;
            #pragma unroll
            for (int dt = 0; dt < 2; ++dt) {
                float4 f;
                f.x = oacc[qg][dt][0] * inv;
                f.y = oacc[qg][dt][1] * inv;
                f.z = oacc[qg][dt][2] * inv;
                f.w = oacc[qg][dt][3] * inv;
                *(float4*)(op + dt * 16 + hi * 4) = f;
            }
        }
    }
}

// ---------------------------------------------------------------------------
// Kernel 3: fused LePE(5x5 dw conv + bias) + o split to bf16 hi/lo,
// plus proj_w hi/lo split (blocks >= M_ROWS).
// ---------------------------------------------------------------------------
__global__ __launch_bounds__(256)
void lepe_conv(const float* __restrict__ o, const float* __restrict__ x,
               const float* __restrict__ lepe_w, const float* __restrict__ lepe_b,
               const float* __restrict__ proj_w,
               unsigned short* __restrict__ ohi, unsigned short* __restrict__ olo,
               unsigned short* __restrict__ pwhi, unsigned short* __restrict__ pwlo)
{
    int blk = blockIdx.x, c = threadIdx.x;
    if (blk < M_ROWS) {
        float val = o[(size_t)blk * CC + c];
        int b = blk / SS, s = blk % SS;
        if (s > 0) {
            int sp = s - 1;
            int xx = sp % WW, y = sp / WW;
            float acc = lepe_b[c];
            const float* wc = lepe_w + c * 25;
            #pragma unroll
            for (int ky = 0; ky < 5; ++ky) {
                int yy = y + ky - 2;
                if (yy < 0 || yy >= HH) continue;
                #pragma unroll
                for (int kx = 0; kx < 5; ++kx) {
                    int xp = xx + kx - 2;
                    if (xp < 0 || xp >= WW) continue;
                    acc += x[(((size_t)b * HH + yy) * WW + xp) * CC + c] * wc[ky * 5 + kx];
                }
            }
            val += acc;
        }
        unsigned short h = f2bf(val);
        ohi[(size_t)blk * CC + c] = h;
        olo[(size_t)blk * CC + c] = f2bf(val - bf2f(h));
    } else {
        int r = blk - M_ROWS;   // 0..255
        float v = proj_w[(size_t)r * CC + c];
        unsigned short h = f2bf(v);
        pwhi[(size_t)r * CC + c] = h;
        pwlo[(size_t)r * CC + c] = f2bf(v - bf2f(h));
    }
}

// ---------------------------------------------------------------------------
// Kernel 4: proj split-bf16 MFMA GEMM: out = (o+lepe) @ proj_w^T + b
// acc = Ahi@Whi + Alo@Whi + Ahi@Wlo  (fp32-grade accuracy).
// ---------------------------------------------------------------------------
__global__ __launch_bounds__(256)
void proj_mfma(const unsigned short* __restrict__ ohi,
               const unsigned short* __restrict__ olo,
               const unsigned short* __restrict__ pwhi,
               const unsigned short* __restrict__ pwlo,
               const float* __restrict__ bias, float* __restrict__ out)
{
    __shared__ unsigned short Ah[64][72];
    __shared__ unsigned short Al[64][72];
    __shared__ unsigned short Wh[64][72];
    __shared__ unsigned short Wl[64][72];
    const int tid = threadIdx.x;
    const int w = tid >> 6, lane = tid & 63, lo = lane & 15, hi = lane >> 4;
    const int row0 = blockIdx.x * 64, col0 = blockIdx.y * 64;
    const int wm = (w & 1) * 32, wn = (w >> 1) * 32;

    f32x4 acc[2][2] = {};

    for (int k0 = 0; k0 < CC; k0 += 64) {
        __syncthreads();
        #pragma unroll
        for (int i = 0; i < 2; ++i) {
            int chunk = tid + i * 256;          // 0..511
            int row = chunk >> 3, c8 = (chunk & 7) * 8;
            int gr = row0 + row;
            short8 ah = {}, al = {};
            if (gr < M_ROWS) {
                ah = *(const short8*)(ohi + (size_t)gr * CC + k0 + c8);
                al = *(const short8*)(olo + (size_t)gr * CC + k0 + c8);
            }
            *(short8*)&Ah[row][c8] = ah;
            *(short8*)&Al[row][c8] = al;
            int wr = col0 + row;
            *(short8*)&Wh[row][c8] = *(const short8*)(pwhi + (size_t)wr * CC + k0 + c8);
            *(short8*)&Wl[row][c8] = *(const short8*)(pwlo + (size_t)wr * CC + k0 + c8);
        }
        __syncthreads();
        #pragma unroll
        for (int kk = 0; kk < 64; kk += 32) {
            short8 ah[2], al[2], wh[2], wl[2];
            #pragma unroll
            for (int m = 0; m < 2; ++m) {
                ah[m] = *(const short8*)&Ah[wm + m * 16 + lo][kk + hi * 8];
                al[m] = *(const short8*)&Al[wm + m * 16 + lo][kk + hi * 8];
            }
            #pragma unroll
            for (int n = 0; n < 2; ++n) {
                wh[n] = *(const short8*)&Wh[wn + n * 16 + lo][kk + hi * 8];
                wl[n] = *(const short8*)&Wl[wn + n * 16 + lo][kk + hi * 8];
            }
            #pragma unroll
            for (int m = 0; m < 2; ++m)
                #pragma unroll
                for (int n = 0; n < 2; ++n) {
                    acc[m][n] = __builtin_amdgcn_mfma_f32_16x16x32_bf16(
                                    ah[m], wh[n], acc[m][n], 0, 0, 0);
                    acc[m][n] = __builtin_amdgcn_mfma_f32_16x16x32_bf16(
                                    al[m], wh[n], acc[m][n], 0, 0, 0);
                    acc[m][n] = __builtin_amdgcn_mfma_f32_16x16x32_bf16(
                                    ah[m], wl[n], acc[m][n], 0, 0, 0);
                }
        }
    }

    #pragma unroll
    for (int m = 0; m < 2; ++m) {
        #pragma unroll
        for (int rr = 0; rr < 4; ++rr) {
            int r = row0 + wm + m * 16 + hi * 4 + rr;
            if (r >= M_ROWS) continue;
            int b = r / SS, s = r % SS;
            #pragma unroll
            for (int n = 0; n < 2; ++n) {
                int col = col0 + wn + n * 16 + lo;
                float val = acc[m][n][rr] + bias[col];
                if (s == 0)
                    out[(size_t)BB * NN * CC + (size_t)b * CC + col] = val;
                else
                    out[((size_t)b * NN + (s - 1)) * CC + col] = val;
            }
        }
    }
}

extern "C" void kernel_launch(void* const* d_in, const int* in_sizes, int n_in,
                              void* d_out, int out_size, void* d_ws, size_t ws_size,
                              hipStream_t stream)
{
    const float* x      = (const float*)d_in[0];
    const float* cls    = (const float*)d_in[1];
    const float* qkv_w  = (const float*)d_in[2];
    const float* proj_w = (const float*)d_in[3];
    const float* proj_b = (const float*)d_in[4];
    const float* lepe_w = (const float*)d_in[5];
    const float* lepe_b = (const float*)d_in[6];
    float* out = (float*)d_out;

    // Workspace overlay (total 32,251,904 B — same proven footprint):
    char* ws = (char*)d_ws;
    unsigned short* qb   = (unsigned short*)(ws + 0);
    unsigned short* kb   = (unsigned short*)(ws + 6424576);
    unsigned short* vt   = (unsigned short*)(ws + 12849152);
    float*          o    = (float*)(ws + 19402752);
    unsigned short* xb   = (unsigned short*)(ws + 19402752);   // aliases o (dead before attn)
    unsigned short* wb   = (unsigned short*)(ws + 25827328);   // aliases o tail
    unsigned short* ohi  = (unsigned short*)(ws + 0);          // aliases qb (dead after attn)
    unsigned short* olo  = (unsigned short*)(ws + 6424576);    // aliases kb
    unsigned short* pwhi = (unsigned short*)(ws + 12849152);   // aliases vt (dead after attn)
    unsigned short* pwlo = (unsigned short*)(ws + 12980224);

    prepare  <<<M_ROWS + 3 * CC + 256, 256, 0, stream>>>(x, cls, qkv_w, xb, wb, vt);
    qkv_mfma <<<dim3(100, 6), 256, 0, stream>>>(xb, wb, qb, kb, vt);
    attn_mfma<<<dim3(25, NH, BB), 256, 0, stream>>>(qb, kb, vt, o);
    lepe_conv<<<M_ROWS + CC, 256, 0, stream>>>(o, x, lepe_w, lepe_b, proj_w,
                                               ohi, olo, pwhi, pwlo);
    proj_mfma<<<dim3(197, 4), 256, 0, stream>>>(ohi, olo, pwhi, pwlo, proj_b, out);
}

// Round 5
// 308.907 us; speedup vs baseline: 4.4682x; 1.0462x over previous
//
#include <hip/hip_runtime.h>
#include <math.h>

#define BB 4
#define HH 56
#define WW 56
#define CC 256
#define NN 3136            // HH*WW
#define SS 3137            // 1 + NN
#define NH 8
#define HD 32
#define M_ROWS (BB * SS)   // 12548
#define SPAD 3200          // padded S for vt rows
#define QSCALE (0.17677669529663687f * 1.4426950408889634f)  // 1/sqrt(32) * log2(e)
#define KT 128             // attention key-tile

typedef short short8 __attribute__((ext_vector_type(8)));   // 8 bf16 (4 VGPRs)
typedef short bf4    __attribute__((ext_vector_type(4)));   // 4 bf16 (2 VGPRs)
typedef float f32x4  __attribute__((ext_vector_type(4)));   // MFMA C/D

static __device__ __forceinline__ unsigned short f2bf(float f) {
    union { float f; unsigned u; } a; a.f = f;
    unsigned r = a.u + 0x7FFF + ((a.u >> 16) & 1);   // RNE
    return (unsigned short)(r >> 16);
}
static __device__ __forceinline__ float bf2f(unsigned short h) {
    union { unsigned u; float f; } a; a.u = ((unsigned)h) << 16; return a.f;
}

// ---------------------------------------------------------------------------
// Kernel 0: prepare — xb = bf16(x_cat), wb = bf16(qkv_w), zero vt pad cols.
// ---------------------------------------------------------------------------
__global__ __launch_bounds__(256)
void prepare(const float* __restrict__ x, const float* __restrict__ cls,
             const float* __restrict__ qkv_w,
             unsigned short* __restrict__ xb, unsigned short* __restrict__ wb,
             unsigned short* __restrict__ vt)
{
    int blk = blockIdx.x, c = threadIdx.x;
    if (blk < M_ROWS) {
        int b = blk / SS, s = blk % SS;
        const float* src = (s == 0) ? (cls + (size_t)b * CC)
                                    : (x + ((size_t)b * NN + (s - 1)) * CC);
        xb[(size_t)blk * CC + c] = f2bf(src[c]);
    } else if (blk < M_ROWS + 3 * CC) {
        int r = blk - M_ROWS;   // 0..767
        wb[(size_t)r * CC + c] = f2bf(qkv_w[(size_t)r * CC + c]);
    } else {
        int base = (blk - (M_ROWS + 3 * CC)) * 4;   // 4 rows per block
        int row = base + (c >> 6);
        int col = 3136 + (c & 63);
        vt[(size_t)row * SPAD + col] = 0;
    }
}

// ---------------------------------------------------------------------------
// Kernel 1: qkv bf16 MFMA GEMM: [12548x256] @ [768x256]^T
// Grid (100,6): batch-aligned M tiles. Epilogue: qb (QSCALE folded), kb,
// vt[(b*8+h)*32+d][s] (V^T, packed short4 stores).
// ---------------------------------------------------------------------------
__global__ __launch_bounds__(256)
void qkv_mfma(const unsigned short* __restrict__ xb,
              const unsigned short* __restrict__ wb,
              unsigned short* __restrict__ qb, unsigned short* __restrict__ kb,
              unsigned short* __restrict__ vt)
{
    __shared__ unsigned short As[128][72];
    __shared__ unsigned short Bs[128][72];
    const int tid = threadIdx.x;
    const int w = tid >> 6, lane = tid & 63, lo = lane & 15, hi = lane >> 4;
    const int b0 = blockIdx.x / 25;
    const int s0blk = (blockIdx.x % 25) * 128;
    const int col0 = blockIdx.y * 128;
    const int wm = (w & 1) * 64, wn = (w >> 1) * 64;

    f32x4 acc[4][4] = {};

    for (int k0 = 0; k0 < CC; k0 += 64) {
        __syncthreads();
        #pragma unroll
        for (int i = 0; i < 4; ++i) {
            int chunk = tid + i * 256;          // 0..1023
            int row = chunk >> 3, c8 = (chunk & 7) * 8;
            short8 av = {};
            if (s0blk + row < SS)
                av = *(const short8*)(xb + (size_t)(b0 * SS + s0blk + row) * CC + k0 + c8);
            *(short8*)&As[row][c8] = av;
            short8 bv = *(const short8*)(wb + (size_t)(col0 + row) * CC + k0 + c8);
            *(short8*)&Bs[row][c8] = bv;
        }
        __syncthreads();
        #pragma unroll
        for (int kk = 0; kk < 64; kk += 32) {
            short8 af[4], bf_[4];
            #pragma unroll
            for (int m = 0; m < 4; ++m)
                af[m] = *(const short8*)&As[wm + m * 16 + lo][kk + hi * 8];
            #pragma unroll
            for (int n = 0; n < 4; ++n)
                bf_[n] = *(const short8*)&Bs[wn + n * 16 + lo][kk + hi * 8];
            #pragma unroll
            for (int m = 0; m < 4; ++m)
                #pragma unroll
                for (int n = 0; n < 4; ++n)
                    acc[m][n] = __builtin_amdgcn_mfma_f32_16x16x32_bf16(
                                    af[m], bf_[n], acc[m][n], 0, 0, 0);
        }
    }

    const int part = col0 >> 8;   // 0=q, 1=k, 2=v (block-uniform)
    if (part < 2) {
        #pragma unroll
        for (int m = 0; m < 4; ++m) {
            #pragma unroll
            for (int rr = 0; rr < 4; ++rr) {
                int s = s0blk + wm + m * 16 + hi * 4 + rr;
                if (s >= SS) continue;
                size_t r = (size_t)(b0 * SS + s);
                #pragma unroll
                for (int n = 0; n < 4; ++n) {
                    int cc = (col0 + wn + n * 16 + lo) & 255;
                    float val = acc[m][n][rr];
                    if (part == 0) qb[r * CC + cc] = f2bf(val * QSCALE);
                    else           kb[r * CC + cc] = f2bf(val);
                }
            }
        }
    } else {
        #pragma unroll
        for (int m = 0; m < 4; ++m) {
            int s0 = s0blk + wm + m * 16 + hi * 4;   // multiple of 4
            if (s0 >= SS) continue;
            bool fast = (s0 + 3 < SS);
            #pragma unroll
            for (int n = 0; n < 4; ++n) {
                int cc = (col0 + wn + n * 16 + lo) & 255;
                int hh = cc >> 5, d = cc & 31;
                unsigned short* vrow = vt + (size_t)((b0 * NH + hh) * HD + d) * SPAD;
                if (fast) {
                    bf4 pk;
                    pk[0] = (short)f2bf(acc[m][n][0]);
                    pk[1] = (short)f2bf(acc[m][n][1]);
                    pk[2] = (short)f2bf(acc[m][n][2]);
                    pk[3] = (short)f2bf(acc[m][n][3]);
                    *(bf4*)(vrow + s0) = pk;
                } else {
                    for (int rr = 0; rr < 4 && s0 + rr < SS; ++rr)
                        vrow[s0 + rr] = f2bf(acc[m][n][rr]);
                }
            }
        }
    }
}

// ---------------------------------------------------------------------------
// Kernel 2: LePE depthwise 5x5 conv + bias -> bf16 [M_ROWS][256]
// (row s=0 per batch = 0; runs after qkv so it can overwrite dead xb space)
// ---------------------------------------------------------------------------
__global__ __launch_bounds__(256)
void lepe_kernel(const float* __restrict__ x, const float* __restrict__ w,
                 const float* __restrict__ bias, unsigned short* __restrict__ lepe)
{
    int blk = blockIdx.x, c = threadIdx.x;
    int b = blk / SS, s = blk % SS;
    unsigned short outv = 0;
    if (s > 0) {
        int sp = s - 1;
        int xx = sp % WW, y = sp / WW;
        float acc = bias[c];
        const float* wc = w + c * 25;
        #pragma unroll
        for (int ky = 0; ky < 5; ++ky) {
            int yy = y + ky - 2;
            if (yy < 0 || yy >= HH) continue;
            #pragma unroll
            for (int kx = 0; kx < 5; ++kx) {
                int xp = xx + kx - 2;
                if (xp < 0 || xp >= WW) continue;
                acc += x[(((size_t)b * HH + yy) * WW + xp) * CC + c] * wc[ky * 5 + kx];
            }
        }
        outv = f2bf(acc);
    }
    lepe[(size_t)blk * CC + c] = outv;
}

// ---------------------------------------------------------------------------
// Kernel 3: bf16 MFMA flash attention, transposed-S; fused +lepe, bf16 out.
//   S^T = K @ Q^T ; P^T = exp2(S^T) packed in-register ; O^T += V^T @ P^T
// Block = (b, h, 64 q); 4 waves x 16 q. KT=128 keys/tile. Grid 1600 blocks.
// Epilogue: ohi = bf16(O/l + lepe).
// ---------------------------------------------------------------------------
__global__ __launch_bounds__(256)
void attn_mfma(const unsigned short* __restrict__ qb,
               const unsigned short* __restrict__ kb,
               const unsigned short* __restrict__ vt,
               const unsigned short* __restrict__ lepe,
               unsigned short* __restrict__ ohi)
{
    __shared__ unsigned short Ks[KT][40];     // 10240 B
    __shared__ unsigned short Vts[32][136];   // 8704 B

    const int tid  = threadIdx.x;
    const int w    = tid >> 6;
    const int lane = tid & 63;
    const int lo   = lane & 15;
    const int hi   = lane >> 4;
    const int h = blockIdx.y;
    const int b = blockIdx.z;
    const int q0w = blockIdx.x * 64 + w * 16;

    const int qrow = min(q0w + lo, SS - 1);
    const short8 qa = *(const short8*)(qb + ((size_t)(b * SS + qrow)) * CC + h * HD + hi * 8);

    f32x4 oacc[2] = {};
    float lp = 0.f;

    const int krow = tid >> 2, kd0 = (tid & 3) * 8;    // K staging: 2 rows/thread
    const int vrow = tid >> 4, vk0 = (tid & 15) * 8;   // V staging: 2 rows/thread
    const unsigned short* kp0 = kb + ((size_t)b * SS + krow) * CC + h * HD + kd0;
    const unsigned short* vp0 = vt + ((size_t)((b * NH + h) * HD + vrow)) * SPAD + vk0;

    for (int k0 = 0; k0 < SPAD; k0 += KT) {
        __syncthreads();
        {
            short8 kv0 = {}, kv1 = {};
            if (k0 + krow < SS)      kv0 = *(const short8*)(kp0 + (size_t)k0 * CC);
            if (k0 + 64 + krow < SS) kv1 = *(const short8*)(kp0 + (size_t)(k0 + 64) * CC);
            *(short8*)&Ks[krow][kd0]      = kv0;
            *(short8*)&Ks[64 + krow][kd0] = kv1;
            short8 vv0 = *(const short8*)(vp0 + k0);
            short8 vv1 = *(const short8*)(vp0 + (size_t)16 * SPAD + k0);
            *(short8*)&Vts[vrow][vk0]      = vv0;
            *(short8*)&Vts[16 + vrow][vk0] = vv1;
        }
        __syncthreads();

        #pragma unroll
        for (int g = 0; g < 8; ++g) {
            short8 kf = *(const short8*)&Ks[g * 16 + lo][hi * 8];
            bf4 vf0 = *(const bf4*)&Vts[lo][g * 16 + hi * 4];
            bf4 vf1 = *(const bf4*)&Vts[16 + lo][g * 16 + hi * 4];
            f32x4 st = __builtin_amdgcn_mfma_f32_16x16x32_bf16(
                           kf, qa, (f32x4){0.f, 0.f, 0.f, 0.f}, 0, 0, 0);
            float p0 = __builtin_amdgcn_exp2f(st[0]);
            float p1 = __builtin_amdgcn_exp2f(st[1]);
            float p2 = __builtin_amdgcn_exp2f(st[2]);
            float p3 = __builtin_amdgcn_exp2f(st[3]);
            lp += (p0 + p1) + (p2 + p3);
            unsigned u01 = __builtin_amdgcn_perm(
                __float_as_uint(p1) + 0x8000u, __float_as_uint(p0) + 0x8000u,
                0x07060302u);
            unsigned u23 = __builtin_amdgcn_perm(
                __float_as_uint(p3) + 0x8000u, __float_as_uint(p2) + 0x8000u,
                0x07060302u);
            union { unsigned u[2]; bf4 s; } pf;
            pf.u[0] = u01; pf.u[1] = u23;
            oacc[0] = __builtin_amdgcn_mfma_f32_16x16x16bf16_1k(vf0, pf.s, oacc[0], 0, 0, 0);
            oacc[1] = __builtin_amdgcn_mfma_f32_16x16x16bf16_1k(vf1, pf.s, oacc[1], 0, 0, 0);
        }
    }

    float l = lp;
    l += __shfl_xor(l, 16);
    l += __shfl_xor(l, 32);
    float inv = 1.f / (l - 63.f);        // remove the 63 pad keys (p=1 each)

    int rowq = q0w + lo;
    if (rowq < SS) {
        size_t base = ((size_t)(b * SS + rowq)) * CC + h * HD;
        #pragma unroll
        for (int dt = 0; dt < 2; ++dt) {
            bf4 lep = *(const bf4*)(lepe + base + dt * 16 + hi * 4);
            bf4 pk;
            #pragma unroll
            for (int r = 0; r < 4; ++r) {
                float val = oacc[dt][r] * inv + bf2f((unsigned short)lep[r]);
                pk[r] = (short)f2bf(val);
            }
            *(bf4*)(ohi + base + dt * 16 + hi * 4) = pk;
        }
    }
}

// ---------------------------------------------------------------------------
// Kernel 4: proj MFMA GEMM: out = ohi @ (Whi+Wlo)^T + b  (W split inline
// from fp32 proj_w during staging). Scatter to (x_out | cls_out).
// ---------------------------------------------------------------------------
__global__ __launch_bounds__(256)
void proj_mfma(const unsigned short* __restrict__ ohi,
               const float* __restrict__ proj_w,
               const float* __restrict__ bias, float* __restrict__ out)
{
    __shared__ unsigned short Ah[64][72];
    __shared__ unsigned short Wh[64][72];
    __shared__ unsigned short Wl[64][72];
    const int tid = threadIdx.x;
    const int w = tid >> 6, lane = tid & 63, lo = lane & 15, hi = lane >> 4;
    const int row0 = blockIdx.x * 64, col0 = blockIdx.y * 64;
    const int wm = (w & 1) * 32, wn = (w >> 1) * 32;

    f32x4 acc[2][2] = {};

    for (int k0 = 0; k0 < CC; k0 += 64) {
        __syncthreads();
        #pragma unroll
        for (int i = 0; i < 2; ++i) {
            int chunk = tid + i * 256;          // 0..511
            int row = chunk >> 3, c8 = (chunk & 7) * 8;
            int gr = row0 + row;
            short8 ah = {};
            if (gr < M_ROWS)
                ah = *(const short8*)(ohi + (size_t)gr * CC + k0 + c8);
            *(short8*)&Ah[row][c8] = ah;
            const float* wp = proj_w + (size_t)(col0 + row) * CC + k0 + c8;
            short8 wh, wl;
            #pragma unroll
            for (int e = 0; e < 8; ++e) {
                float v = wp[e];
                unsigned short hh = f2bf(v);
                wh[e] = (short)hh;
                wl[e] = (short)f2bf(v - bf2f(hh));
            }
            *(short8*)&Wh[row][c8] = wh;
            *(short8*)&Wl[row][c8] = wl;
        }
        __syncthreads();
        #pragma unroll
        for (int kk = 0; kk < 64; kk += 32) {
            short8 ah[2], wh[2], wl[2];
            #pragma unroll
            for (int m = 0; m < 2; ++m)
                ah[m] = *(const short8*)&Ah[wm + m * 16 + lo][kk + hi * 8];
            #pragma unroll
            for (int n = 0; n < 2; ++n) {
                wh[n] = *(const short8*)&Wh[wn + n * 16 + lo][kk + hi * 8];
                wl[n] = *(const short8*)&Wl[wn + n * 16 + lo][kk + hi * 8];
            }
            #pragma unroll
            for (int m = 0; m < 2; ++m)
                #pragma unroll
                for (int n = 0; n < 2; ++n) {
                    acc[m][n] = __builtin_amdgcn_mfma_f32_16x16x32_bf16(
                                    ah[m], wh[n], acc[m][n], 0, 0, 0);
                    acc[m][n] = __builtin_amdgcn_mfma_f32_16x16x32_bf16(
                                    ah[m], wl[n], acc[m][n], 0, 0, 0);
                }
        }
    }

    #pragma unroll
    for (int m = 0; m < 2; ++m) {
        #pragma unroll
        for (int rr = 0; rr < 4; ++rr) {
            int r = row0 + wm + m * 16 + hi * 4 + rr;
            if (r >= M_ROWS) continue;
            int b = r / SS, s = r % SS;
            #pragma unroll
            for (int n = 0; n < 2; ++n) {
                int col = col0 + wn + n * 16 + lo;
                float val = acc[m][n][rr] + bias[col];
                if (s == 0)
                    out[(size_t)BB * NN * CC + (size_t)b * CC + col] = val;
                else
                    out[((size_t)b * NN + (s - 1)) * CC + col] = val;
            }
        }
    }
}

extern "C" void kernel_launch(void* const* d_in, const int* in_sizes, int n_in,
                              void* d_out, int out_size, void* d_ws, size_t ws_size,
                              hipStream_t stream)
{
    const float* x      = (const float*)d_in[0];
    const float* cls    = (const float*)d_in[1];
    const float* qkv_w  = (const float*)d_in[2];
    const float* proj_w = (const float*)d_in[3];
    const float* proj_b = (const float*)d_in[4];
    const float* lepe_w = (const float*)d_in[5];
    const float* lepe_b = (const float*)d_in[6];
    float* out = (float*)d_out;

    // Workspace overlay (total 32,251,904 B — proven footprint):
    //   [0        ) qb   6.42M
    //   [6424576  ) kb   6.42M
    //   [12849152 ) vt   6.55M
    //   [19402752 ) xb   6.42M  -> after qkv: lepe bf16 (written by lepe_kernel)
    //   [25827328 ) wb   0.39M  -> after qkv: ohi bf16 6.42M (written by attn)
    char* ws = (char*)d_ws;
    unsigned short* qb   = (unsigned short*)(ws + 0);
    unsigned short* kb   = (unsigned short*)(ws + 6424576);
    unsigned short* vt   = (unsigned short*)(ws + 12849152);
    unsigned short* xb   = (unsigned short*)(ws + 19402752);
    unsigned short* wb   = (unsigned short*)(ws + 25827328);
    unsigned short* lepe = (unsigned short*)(ws + 19402752);   // over dead xb
    unsigned short* ohi  = (unsigned short*)(ws + 25827328);   // over dead wb

    prepare    <<<M_ROWS + 3 * CC + 256, 256, 0, stream>>>(x, cls, qkv_w, xb, wb, vt);
    qkv_mfma   <<<dim3(100, 6), 256, 0, stream>>>(xb, wb, qb, kb, vt);
    lepe_kernel<<<M_ROWS, 256, 0, stream>>>(x, lepe_w, lepe_b, lepe);
    attn_mfma  <<<dim3(50, NH, BB), 256, 0, stream>>>(qb, kb, vt, lepe, ohi);
    proj_mfma  <<<dim3(197, 4), 256, 0, stream>>>(ohi, proj_w, proj_b, out);
}